// Round 4
// baseline (33.421 us; speedup 1.0000x reference)
//
#include <hip/hip_runtime.h>

// Problem constants (fixed by the bench: B=8, L=512, T=4096, D=512).
constexpr int B = 8;
constexpr int L = 512;
constexpr int D = 512;
constexpr int T = 4096;
constexpr int ROWS = 4;                   // d-rows per block (1 per wave)
constexpr int RG   = D / ROWS;            // 128 row-groups

constexpr int OUT_REP = B * D * T;        // offset of repeats in d_out
constexpr int OUT_LAT = OUT_REP + B * L;  // offset of latent_lengths

__global__ __launch_bounds__(256) void encoder_expand_kernel(
    const float* __restrict__ enc,   // (B, D, L)
    const float* __restrict__ dur,   // (B, L)
    float* __restrict__ out)         // [expanded (B,D,T) | repeats (B,L) | latent (B)]
{
    const int rg   = blockIdx.x;            // 0..RG-1
    const int b    = blockIdx.y;            // 0..B-1
    const int tid  = threadIdx.x;
    const int lane = tid & 63;
    const int wave = tid >> 6;              // 0..3

    __shared__ int lut[T];                  // t -> l map (16 KB), -1 = past end
    __shared__ int wave_tot[4];

    // ---- issue dur load (8 B/lane, coalesced) ----
    const float2 dur2 = *reinterpret_cast<const float2*>(dur + b * L + 2 * tid);

    // ---- init lut to -1 while the load is in flight ----
    const int4 neg1 = make_int4(-1, -1, -1, -1);
    #pragma unroll
    for (int k = 0; k < T / (4 * 256); ++k)        // 4x int4 per thread
        *reinterpret_cast<int4*>(&lut[(k * 256 + tid) * 4]) = neg1;

    // ---- repeats + exclusive scan over L=512 (2 elems/thread) ----
    const int r0 = (int)floorf(dur2.x + 0.5f);
    const int r1 = (int)floorf(dur2.y + 0.5f);
    const int pair = r0 + r1;

    int scan = pair;                        // wave-level inclusive scan of pair sums
    #pragma unroll
    for (int off = 1; off < 64; off <<= 1) {
        int n = __shfl_up(scan, off, 64);
        if (lane >= off) scan += n;
    }
    if (lane == 63) wave_tot[wave] = scan;
    __syncthreads();                        // covers lut init + wave_tot

    int wpre = 0;
    #pragma unroll
    for (int w = 0; w < 4; ++w) wpre += (w < wave) ? wave_tot[w] : 0;
    int k = wpre + scan - pair;             // exclusive prefix of this thread's pair
    const int total = wave_tot[0] + wave_tot[1] + wave_tot[2] + wave_tot[3];

    // ---- scatter: each l writes its own span into lut (no binary search) ----
    const int l0 = 2 * tid;
    for (int q = 0; q < r0; ++q) { if (k < T) lut[k] = l0;     ++k; }
    for (int q = 0; q < r1; ++q) { if (k < T) lut[k] = l0 + 1; ++k; }
    __syncthreads();

    // ---- side outputs (one row-group per batch) ----
    if (rg == 0) {
        out[OUT_REP + b * L + l0]     = (float)r0;
        out[OUT_REP + b * L + l0 + 1] = (float)r1;
        if (tid == 0) out[OUT_LAT + b] = (float)total;
    }

    // ---- streaming expansion: each wave owns ONE full d-row (16 KB),
    //      written as 16 sequential 1 KB store instructions (fill-like) ----
    const int d = rg * ROWS + wave;
    const float* encrow = enc + ((size_t)b * D + d) * L;
    float*       outrow = out + ((size_t)b * D + d) * T;

    #pragma unroll 8
    for (int j = 0; j < 16; ++j) {
        const int t = j * 256 + 4 * lane;
        const int4 l4 = *reinterpret_cast<const int4*>(&lut[t]);
        // branchless: clamp index (always valid), then mask to zero
        const int ia = l4.x < 0 ? 0 : l4.x;
        const int ib = l4.y < 0 ? 0 : l4.y;
        const int ic = l4.z < 0 ? 0 : l4.z;
        const int id = l4.w < 0 ? 0 : l4.w;
        float4 v;
        v.x = encrow[ia];
        v.y = encrow[ib];
        v.z = encrow[ic];
        v.w = encrow[id];
        if (l4.x < 0) v.x = 0.0f;
        if (l4.y < 0) v.y = 0.0f;
        if (l4.z < 0) v.z = 0.0f;
        if (l4.w < 0) v.w = 0.0f;
        *reinterpret_cast<float4*>(&outrow[t]) = v;
    }
}

extern "C" void kernel_launch(void* const* d_in, const int* in_sizes, int n_in,
                              void* d_out, int out_size, void* d_ws, size_t ws_size,
                              hipStream_t stream) {
    const float* enc = (const float*)d_in[0];   // (B, D, L) fp32
    const float* dur = (const float*)d_in[1];   // (B, L)    fp32
    float* out = (float*)d_out;
    encoder_expand_kernel<<<dim3(RG, B), dim3(256), 0, stream>>>(enc, dur, out);
}

// Round 5
// 21.603 us; speedup vs baseline: 1.5471x; 1.5471x over previous
//
#include <hip/hip_runtime.h>

// Problem constants (fixed by the bench: B=8, L=512, T=4096, D=512).
constexpr int B = 8;
constexpr int L = 512;
constexpr int D = 512;
constexpr int T = 4096;
constexpr int GR = 8;                     // d-rows per block
constexpr int TQ = 4;                     // t-windows
constexpr int TW = T / TQ;                // 1024 t per window

constexpr int OUT_REP = B * D * T;        // offset of repeats in d_out
constexpr int OUT_LAT = OUT_REP + B * L;  // offset of latent_lengths

__global__ __launch_bounds__(256, 8) void encoder_expand_kernel(
    const float* __restrict__ enc,   // (B, D, L)
    const float* __restrict__ dur,   // (B, L)
    float* __restrict__ out)         // [expanded (B,D,T) | repeats (B,L) | latent (B)]
{
    const int dg   = blockIdx.x >> 2;       // 0..63  d-group (8 rows)
    const int tq   = blockIdx.x & 3;        // 0..3   t-window
    const int b    = blockIdx.y;
    const int tid  = threadIdx.x;
    const int lane = tid & 63;
    const int wave = tid >> 6;              // 0..3
    const int w0   = tq * TW;

    __shared__ float encsm[GR * L];         // 16 KB staged enc rows
    __shared__ unsigned short lut16[TW];    // 2 KB t->l map, 0xFFFF = past end
    __shared__ int wave_tot[4];

    // ---- issue independent global loads first ----
    const float2 dur2 = *reinterpret_cast<const float2*>(dur + b * L + 2 * tid);

    const float* encb = enc + ((size_t)b * D + (size_t)dg * GR) * L;  // 8 rows, contiguous
    const float4 s0 = reinterpret_cast<const float4*>(encb)[tid];
    const float4 s1 = reinterpret_cast<const float4*>(encb)[tid + 256];
    const float4 s2 = reinterpret_cast<const float4*>(encb)[tid + 512];
    const float4 s3 = reinterpret_cast<const float4*>(encb)[tid + 768];

    // ---- init LUT sentinel (512 ints) ----
    reinterpret_cast<int*>(lut16)[tid]       = -1;
    reinterpret_cast<int*>(lut16)[tid + 256] = -1;

    // ---- stage enc rows into LDS (same flat layout as global) ----
    reinterpret_cast<float4*>(encsm)[tid]       = s0;
    reinterpret_cast<float4*>(encsm)[tid + 256] = s1;
    reinterpret_cast<float4*>(encsm)[tid + 512] = s2;
    reinterpret_cast<float4*>(encsm)[tid + 768] = s3;

    // ---- repeats + scan over L=512 (2 elems/thread) ----
    const int r0 = (int)floorf(dur2.x + 0.5f);
    const int r1 = (int)floorf(dur2.y + 0.5f);
    const int pair = r0 + r1;

    int scan = pair;
    #pragma unroll
    for (int off = 1; off < 64; off <<= 1) {
        int n = __shfl_up(scan, off, 64);
        if (lane >= off) scan += n;
    }
    if (lane == 63) wave_tot[wave] = scan;
    __syncthreads();                        // lut init + encsm + wave_tot done

    int wpre = 0;
    #pragma unroll
    for (int w = 0; w < 4; ++w) wpre += (w < wave) ? wave_tot[w] : 0;
    int k = wpre + scan - pair;             // global t-start of l0's span
    const int total = wave_tot[0] + wave_tot[1] + wave_tot[2] + wave_tot[3];

    // ---- scatter: each l writes its own span into the window LUT ----
    const int l0 = 2 * tid;
    for (int q = 0; q < r0; ++q, ++k) {
        const unsigned j = (unsigned)(k - w0);
        if (j < (unsigned)TW) lut16[j] = (unsigned short)l0;
    }
    for (int q = 0; q < r1; ++q, ++k) {
        const unsigned j = (unsigned)(k - w0);
        if (j < (unsigned)TW) lut16[j] = (unsigned short)(l0 + 1);
    }

    // ---- side outputs (one block per batch) ----
    if (dg == 0 && tq == 0) {
        out[OUT_REP + b * L + l0]     = (float)r0;
        out[OUT_REP + b * L + l0 + 1] = (float)r1;
        if (tid == 0) out[OUT_LAT + b] = (float)total;
    }
    __syncthreads();                        // scatter done

    // ---- payload: 32 (row, 256-t-seg) tiles, 8 independent per wave ----
    #pragma unroll
    for (int i = 0; i < 8; ++i) {
        const int tile = wave + 4 * i;
        const int row  = tile >> 2;         // 0..7
        const int seg  = tile & 3;          // 0..3
        const int t    = seg * 256 + 4 * lane;

        const uint2 lu = *reinterpret_cast<const uint2*>(&lut16[t]);
        const int la = lu.x & 0xffff, lb = lu.x >> 16;
        const int lc = lu.y & 0xffff, ld = lu.y >> 16;

        const float* rowp = encsm + row * L;
        float4 v;
        v.x = rowp[la & 511];               // monotone l across lanes -> ~2-way banks (free)
        v.y = rowp[lb & 511];
        v.z = rowp[lc & 511];
        v.w = rowp[ld & 511];
        if (la == 0xffff) v.x = 0.0f;
        if (lb == 0xffff) v.y = 0.0f;
        if (lc == 0xffff) v.z = 0.0f;
        if (ld == 0xffff) v.w = 0.0f;

        float* dst = out + ((size_t)b * D + (size_t)dg * GR + row) * T + w0 + t;
        *reinterpret_cast<float4*>(dst) = v;   // 1 KB contiguous per wave store
    }
}

extern "C" void kernel_launch(void* const* d_in, const int* in_sizes, int n_in,
                              void* d_out, int out_size, void* d_ws, size_t ws_size,
                              hipStream_t stream) {
    const float* enc = (const float*)d_in[0];   // (B, D, L) fp32
    const float* dur = (const float*)d_in[1];   // (B, L)    fp32
    float* out = (float*)d_out;
    encoder_expand_kernel<<<dim3((D / GR) * TQ, B), dim3(256), 0, stream>>>(enc, dur, out);
}